// Round 1
// baseline (135.759 us; speedup 1.0000x reference)
//
#include <hip/hip_runtime.h>

// PDE2DReservoir: linear diffusion + sparse delta forcing + sparse readout.
// U_final = sum_s DT*f_s * A^(63-s) * F  with F = sum_j vals_j * delta_{p_j}
// => measured[m] = sum_j vals_j * K(m - p_j), K a 127x127 Green's stencil
//    (Manhattan radius <= 63 << 2048, so periodic wrap == free space).

#define N_INJ   4096
#define N_MEAS  4096
#define KD      128     // small simulation domain
#define KC      64      // delta at center (KC,KC)
#define STEPS   64
#define WRAP_M  4095

__device__ float g_K[KD * KD];
__device__ float g_vals[N_INJ];

__global__ __launch_bounds__(256) void vals_kernel(const float* __restrict__ u_t,
                                                   const float* __restrict__ scales,
                                                   const int* __restrict__ dims) {
    int j = blockIdx.x * 256 + threadIdx.x;
    if (j < N_INJ) g_vals[j] = scales[j] * u_t[dims[j]];
}

// Single block, 1024 threads, 16 contiguous cells each (one 128x128 LDS buffer).
// Single-buffer Jacobi: read phase -> barrier -> write phase -> barrier.
// Diamond gating: at step s only cells with Manhattan dist <= s from center
// can be nonzero; inactive threads skip all LDS traffic (still hit barriers).
__global__ __launch_bounds__(1024) void green_kernel() {
    __shared__ float U[KD * KD];                 // 64 KB
    const int t = threadIdx.x;
    const int base = t << 4;                     // first cell (16 per thread)
    const int row  = base >> 7;                  // 0..127
    const int col0 = base & 127;                 // 0,16,...,112
    float4* U4 = reinterpret_cast<float4*>(U);

#pragma unroll
    for (int q = 0; q < 4; ++q) U4[(t << 2) + q] = float4{0.f, 0.f, 0.f, 0.f};
    __syncthreads();

    const float cc = 0.025f;                     // DT*DIFF/DX^2
    const int rd = (row > KC) ? (row - KC) : (KC - row);
    const int cd = (col0 + 15 < KC) ? (KC - (col0 + 15))
                                    : ((col0 > KC) ? (col0 - KC) : 0);
    const int dist0 = rd + cd;                   // min Manhattan dist of run
    const bool has_force = (row == KC) && (col0 == KC);  // cell (64,64) is i=0

    for (int s = 0; s < STEPS; ++s) {
        const bool active = (dist0 <= s);
        float nv[16];
        if (active) {
            float own[16];
#pragma unroll
            for (int q = 0; q < 4; ++q) {
                float4 v = U4[(t << 2) + q];
                own[q * 4 + 0] = v.x; own[q * 4 + 1] = v.y;
                own[q * 4 + 2] = v.z; own[q * 4 + 3] = v.w;
            }
            const float lft = (col0 == 0)   ? 0.f : U[base - 1];
            const float rgt = (col0 == 112) ? 0.f : U[base + 16];
#pragma unroll
            for (int q = 0; q < 4; ++q) {
                float4 u4, d4;
                if (row == 0)   u4 = float4{0.f, 0.f, 0.f, 0.f};
                else            u4 = U4[((base - 128) >> 2) + q];
                if (row == 127) d4 = float4{0.f, 0.f, 0.f, 0.f};
                else            d4 = U4[((base + 128) >> 2) + q];
                const float up[4] = {u4.x, u4.y, u4.z, u4.w};
                const float dn[4] = {d4.x, d4.y, d4.z, d4.w};
#pragma unroll
                for (int k = 0; k < 4; ++k) {
                    const int i = q * 4 + k;
                    const float l = (i == 0)  ? lft : own[i - 1];
                    const float r = (i == 15) ? rgt : own[i + 1];
                    nv[i] = own[i] + cc * (up[k] + dn[k] + l + r - 4.f * own[i]);
                }
            }
            if (has_force) {
                // DT * sin(2*pi*s/64) = DT * sin(s * pi/32)
                nv[0] += 0.001f * sinf(0.09817477042468103f * (float)s);
            }
        }
        __syncthreads();                          // all reads done
        if (active) {
#pragma unroll
            for (int q = 0; q < 4; ++q)
                U4[(t << 2) + q] = float4{nv[q * 4 + 0], nv[q * 4 + 1],
                                          nv[q * 4 + 2], nv[q * 4 + 3]};
        }
        __syncthreads();                          // all writes done
    }

    float4* gK4 = reinterpret_cast<float4*>(g_K);
#pragma unroll
    for (int q = 0; q < 4; ++q) gK4[(t << 2) + q] = U4[(t << 2) + q];
}

// One block per measurement; 256 threads scan all 4096 injections.
__global__ __launch_bounds__(256) void measure_kernel(const int* __restrict__ iix,
                                                      const int* __restrict__ iiy,
                                                      const int* __restrict__ mix,
                                                      const int* __restrict__ miy,
                                                      float* __restrict__ out) {
    const int m  = blockIdx.x;
    const int mx = mix[m];
    const int my = miy[m];
    float acc = 0.f;
    for (int j = threadIdx.x; j < N_INJ; j += 256) {
        int dx = (mx - iix[j]) & WRAP_M; if (dx >= 2048) dx -= 4096;
        int dy = (my - iiy[j]) & WRAP_M; if (dy >= 2048) dy -= 4096;
        const int adx = dx < 0 ? -dx : dx;
        const int ady = dy < 0 ? -dy : dy;
        if (adx + ady <= 63) {
            acc += g_vals[j] * g_K[(KC + dx) * KD + (KC + dy)];
        }
    }
#pragma unroll
    for (int off = 32; off > 0; off >>= 1) acc += __shfl_down(acc, off, 64);
    __shared__ float part[4];
    const int lane = threadIdx.x & 63;
    const int wid  = threadIdx.x >> 6;
    if (lane == 0) part[wid] = acc;
    __syncthreads();
    if (threadIdx.x == 0) out[m] = (part[0] + part[1]) + (part[2] + part[3]);
}

extern "C" void kernel_launch(void* const* d_in, const int* in_sizes, int n_in,
                              void* d_out, int out_size, void* d_ws, size_t ws_size,
                              hipStream_t stream) {
    const float* u_t        = (const float*)d_in[0];
    const float* inj_scales = (const float*)d_in[1];
    const int*   inj_dims   = (const int*)d_in[2];
    const int*   inj_ix     = (const int*)d_in[3];
    const int*   inj_iy     = (const int*)d_in[4];
    const int*   meas_ix    = (const int*)d_in[5];
    const int*   meas_iy    = (const int*)d_in[6];
    float*       out        = (float*)d_out;

    hipLaunchKernelGGL(vals_kernel, dim3(N_INJ / 256), dim3(256), 0, stream,
                       u_t, inj_scales, inj_dims);
    hipLaunchKernelGGL(green_kernel, dim3(1), dim3(1024), 0, stream);
    hipLaunchKernelGGL(measure_kernel, dim3(N_MEAS), dim3(256), 0, stream,
                       inj_ix, inj_iy, meas_ix, meas_iy, out);
}

// Round 2
// 27.655 us; speedup vs baseline: 4.9091x; 4.9091x over previous
//
#include <hip/hip_runtime.h>

// PDE2DReservoir — spectral Green's-function formulation.
//
// U_final = sum_s DT*f_s * A^(63-s) * F,  A = I + c*L (5-point, periodic),
// F = sum_j vals_j * delta_{p_j}.  Hence measured[m] = sum_j vals_j * K(m-p_j)
// with K a fixed 127-radius stencil. Support radius <= 63 << 2048, so the
// 4096-periodic kernel equals the free-space kernel, which we compute on a
// 128-periodic domain spectrally:
//   lambda(wx,wy) = 0.9 + 0.05*(cos tx + cos ty)        (c = DT*DIFF/DX^2)
//   Khat = DT * sum_s f_s lambda^(63-s)   (Horner, deg 63)
//   K = (1/128^2) * separable inverse cosine transform of Khat.

#define N_INJ   4096
#define N_MEAS  4096
#define ND      128
#define STEPS   64
#define WRAP_M  4095

__device__ float g_K[ND * ND];      // Green's stencil, delta at (0,0), 128-periodic
__device__ float g_B[ND * ND];      // intermediate: B[wx][y]
__device__ float g_vals[N_INJ];
__device__ int   g_pack[N_INJ];     // (ix<<12) | iy

// Blocks 0..127: row wx of the first cosine-transform pass.
// Blocks 128..159: vals + packed injection coords.
__global__ __launch_bounds__(128) void spectral_a(const float* __restrict__ u_t,
                                                  const float* __restrict__ scales,
                                                  const int* __restrict__ dims,
                                                  const int* __restrict__ iix,
                                                  const int* __restrict__ iiy) {
    const int b = blockIdx.x;
    const int t = threadIdx.x;
    if (b >= ND) {
        const int j = (b - ND) * 128 + t;          // 32 blocks * 128 = 4096
        g_vals[j] = scales[j] * u_t[dims[j]];
        g_pack[j] = (iix[j] << 12) | iiy[j];
        return;
    }
    __shared__ float ctab[ND];       // cos(2*pi*i/128)
    __shared__ float coeff[STEPS];   // DT * sin(2*pi*s/64)
    __shared__ float khat[ND];       // Khat(wx=b, wy)
    ctab[t] = cosf(0.049087385212340517f * (float)t);
    if (t < STEPS) coeff[t] = 0.001f * sinf(0.09817477042468103f * (float)t);
    __syncthreads();

    // Horner: Khat = sum_s coeff[s] * lambda^(63-s)
    const float lam = 0.9f + 0.05f * (ctab[b] + ctab[t]);
    float h = coeff[0];
#pragma unroll
    for (int s = 1; s < STEPS; ++s) h = fmaf(h, lam, coeff[s]);
    khat[t] = h;
    __syncthreads();

    // B(b, y=t) = sum_wy khat[wy] * cos(2*pi*wy*t/128)
    float acc = 0.f;
#pragma unroll 8
    for (int wy = 0; wy < ND; ++wy)
        acc = fmaf(khat[wy], ctab[(wy * t) & (ND - 1)], acc);
    g_B[b * ND + t] = acc;
}

// Block x, thread y: K(x,y) = (1/16384) * sum_wx B[wx][y] * cos(2*pi*wx*x/128)
__global__ __launch_bounds__(128) void spectral_b() {
    const int x = blockIdx.x;
    const int t = threadIdx.x;
    __shared__ float ctab[ND];
    ctab[t] = cosf(0.049087385212340517f * (float)t);
    __syncthreads();
    float acc = 0.f;
#pragma unroll 8
    for (int wx = 0; wx < ND; ++wx)
        acc = fmaf(g_B[wx * ND + t], ctab[(wx * x) & (ND - 1)], acc);
    g_K[x * ND + t] = acc * (1.f / 16384.f);
}

// One block per measurement; 256 threads scan all 4096 injections (one packed
// int each, L1-resident). Hits (|dx|,|dy| <= 63, ~2 per measurement) gather K.
__global__ __launch_bounds__(256) void measure_kernel(const int* __restrict__ mix,
                                                      const int* __restrict__ miy,
                                                      float* __restrict__ out) {
    const int m  = blockIdx.x;
    const int mx = mix[m];
    const int my = miy[m];
    float acc = 0.f;
#pragma unroll 4
    for (int j = threadIdx.x; j < N_INJ; j += 256) {
        const int p  = g_pack[j];
        const int a  = (mx - (p >> 12)) & WRAP_M;   // dx mod 4096, in [0,4095]
        const int c  = (my - (p & WRAP_M)) & WRAP_M;
        const int ax = a < 2048 ? a : 4096 - a;     // |dx| folded
        const int ay = c < 2048 ? c : 4096 - c;
        if (ax < 64 && ay < 64) {
            // K is 128-periodic and 4096 % 128 == 0, so index = mod-128 residue
            acc += g_vals[j] * g_K[((a & (ND - 1)) << 7) + (c & (ND - 1))];
        }
    }
#pragma unroll
    for (int off = 32; off > 0; off >>= 1) acc += __shfl_down(acc, off, 64);
    __shared__ float part[4];
    const int lane = threadIdx.x & 63;
    const int wid  = threadIdx.x >> 6;
    if (lane == 0) part[wid] = acc;
    __syncthreads();
    if (threadIdx.x == 0) out[m] = (part[0] + part[1]) + (part[2] + part[3]);
}

extern "C" void kernel_launch(void* const* d_in, const int* in_sizes, int n_in,
                              void* d_out, int out_size, void* d_ws, size_t ws_size,
                              hipStream_t stream) {
    const float* u_t        = (const float*)d_in[0];
    const float* inj_scales = (const float*)d_in[1];
    const int*   inj_dims   = (const int*)d_in[2];
    const int*   inj_ix     = (const int*)d_in[3];
    const int*   inj_iy     = (const int*)d_in[4];
    const int*   meas_ix    = (const int*)d_in[5];
    const int*   meas_iy    = (const int*)d_in[6];
    float*       out        = (float*)d_out;

    hipLaunchKernelGGL(spectral_a, dim3(ND + N_INJ / 128), dim3(128), 0, stream,
                       u_t, inj_scales, inj_dims, inj_ix, inj_iy);
    hipLaunchKernelGGL(spectral_b, dim3(ND), dim3(128), 0, stream);
    hipLaunchKernelGGL(measure_kernel, dim3(N_MEAS), dim3(256), 0, stream,
                       meas_ix, meas_iy, out);
}